// Round 1
// baseline (99.655 us; speedup 1.0000x reference)
//
#include <hip/hip_runtime.h>

#define T_LEN 41
#define K_LEN 28
#define LANES_PER_ROW 32

// One row per 32-lane group; lane index within group = k (0..27 produce output,
// lanes 28..31 compute but don't store). Each lane walks t = 0..40 keeping the
// running cumsums in registers (same-address loads within a group broadcast),
// and accumulates the Gaussian-weighted sums for its k. The 1/BANDWIDTH factor
// cancels under the per-(b,k) normalization over t, so it's omitted.
__global__ __launch_bounds__(256) void PILCAL_kernel(
    const float* __restrict__ instock,
    const float* __restrict__ futured,
    const float* __restrict__ lead_pred,
    float* __restrict__ out,
    int B)
{
    const int tid = blockIdx.x * blockDim.x + threadIdx.x;
    const int row = tid >> 5;            // 32 lanes per row
    const int k   = tid & (LANES_PER_ROW - 1);
    if (row >= B) return;

    const float* __restrict__ f = futured + row * T_LEN;
    const float* __restrict__ s = instock + row * T_LEN;

    // lead_scale = clip(lead*13 + 1, 1, 14); kernel center for this lane's k
    const float ls = fminf(fmaxf(lead_pred[row] * 13.0f + 1.0f, 1.0f), 14.0f);
    const float c  = ls + (float)k;
    const float inv_bw = 1.0f / 0.3f;

    // t = 0: head = relu(diff0); idx = 1
    float fc = f[0];
    float ic = s[0];
    float oc = fmaxf(ic - fc, 0.0f);
    float z  = (1.0f - c) * inv_bw;
    float w  = __expf(-0.5f * z * z);
    float wsum = w;
    float accd = w * fc;
    float acco = w * oc;

#pragma unroll
    for (int t = 1; t < T_LEN; ++t) {
        fc += f[t];
        ic += s[t];
        oc = fmaxf(oc, ic - fc);          // cummax of diff
        z  = ((float)(t + 1) - c) * inv_bw;
        w  = __expf(-0.5f * z * z);
        wsum += w;
        accd = fmaf(w, fc, accd);
        acco = fmaf(w, oc, acco);
    }

    if (k < K_LEN) {
        out[row * K_LEN + k] = ic - (accd + acco) / wsum;
    }
}

extern "C" void kernel_launch(void* const* d_in, const int* in_sizes, int n_in,
                              void* d_out, int out_size, void* d_ws, size_t ws_size,
                              hipStream_t stream) {
    const float* instock   = (const float*)d_in[0];
    const float* futured   = (const float*)d_in[1];
    const float* lead_pred = (const float*)d_in[2];
    float* out = (float*)d_out;

    const int B = in_sizes[0] / T_LEN;            // 65536
    const int total_threads = B * LANES_PER_ROW;  // 2M
    const int block = 256;
    const int grid = (total_threads + block - 1) / block;

    PILCAL_kernel<<<grid, block, 0, stream>>>(instock, futured, lead_pred, out, B);
}

// Round 3
// 82.647 us; speedup vs baseline: 1.2058x; 1.2058x over previous
//
#include <hip/hip_runtime.h>

#define T_LEN 41
#define K_LEN 28
#define ROWS_PER_BLOCK 8
#define BLOCK 256

// Phase A: per-row cumsums (futured, instock) + cummax(diff) via 32-lane
// shuffle prefix scans (main 32 + tail 9), stored once to LDS as float2{FC,OC}.
// Phase B: Gaussian with sigma=0.3 has support ~[-2,2]; only integer taps
// i = floor(ls)+k+j, j in {-1,0,1,2} contribute (excluded terms < e^-22,
// ~1e-6 absolute after normalization). Weights depend only on j - frac(ls):
// 4 exps per row. Truncation to i in [1,41] matches the reference sum range.
__global__ __launch_bounds__(BLOCK) void pil_kernel(
    const float* __restrict__ instock,
    const float* __restrict__ futured,
    const float* __restrict__ lead_pred,
    float* __restrict__ out, int B)
{
    __shared__ float2 lds[ROWS_PER_BLOCK][T_LEN];   // {FC[i], OC[i]} at [i-1]

    const int g    = threadIdx.x >> 5;
    const int lane = threadIdx.x & 31;
    const int row  = blockIdx.x * ROWS_PER_BLOCK + g;

    const float lead = lead_pred[row];               // broadcast within group

    const float* __restrict__ f = futured + row * T_LEN;
    const float* __restrict__ s = instock + row * T_LEN;

    // ---- loads: t = lane (0..31) and tail t = 32+lane (lane<9) ----
    float fa = f[lane];
    float sa = s[lane];
    float fb = 0.f, sb = 0.f;
    if (lane < T_LEN - 32) { fb = f[32 + lane]; sb = s[32 + lane]; }

    // ---- inclusive add-scans over the 32-lane group ----
    #pragma unroll
    for (int d = 1; d < 32; d <<= 1) {
        float tf = __shfl_up(fa, d, 32);
        float ts = __shfl_up(sa, d, 32);
        fa = (lane >= d) ? fa + tf : fa;
        sa = (lane >= d) ? sa + ts : sa;
    }
    const float fc31 = __shfl(fa, 31, 32);
    const float ic31 = __shfl(sa, 31, 32);

    // tail scan: 9 elements in lanes 0..8 (d up to 8 suffices)
    #pragma unroll
    for (int d = 1; d < 16; d <<= 1) {
        float tf = __shfl_up(fb, d, 32);
        float ts = __shfl_up(sb, d, 32);
        fb = (lane >= d) ? fb + tf : fb;
        sb = (lane >= d) ? sb + ts : sb;
    }
    fb += fc31;
    sb += ic31;

    const float ic41 = __shfl(sb, 8, 32);            // instock_cumsum[:, -1]

    // ---- cummax of diff, head relu at t=0 ----
    float da = sa - fa;
    if (lane == 0) da = fmaxf(da, 0.f);
    #pragma unroll
    for (int d = 1; d < 32; d <<= 1) {
        float t0 = __shfl_up(da, d, 32);
        da = (lane >= d) ? fmaxf(da, t0) : da;
    }
    const float m31 = __shfl(da, 31, 32);
    float db = sb - fb;
    #pragma unroll
    for (int d = 1; d < 16; d <<= 1) {
        float t0 = __shfl_up(db, d, 32);
        db = (lane >= d) ? fmaxf(db, t0) : db;
    }
    db = fmaxf(db, m31);

    // ---- stash {FC, OC} ----
    lds[g][lane] = make_float2(fa, da);
    if (lane < T_LEN - 32) lds[g][32 + lane] = make_float2(fb, db);

    __syncthreads();

    // ---- phase B: 4 taps per output k = lane ----
    if (lane < K_LEN) {
        const float ls = fminf(fmaxf(lead * 13.0f + 1.0f, 1.0f), 14.0f);
        const float Ff = floorf(ls);
        const float r  = ls - Ff;
        const int   Fi = (int)Ff;
        const float inv_bw = 1.0f / 0.3f;

        float wsum = 0.f, accd = 0.f, acco = 0.f;
        #pragma unroll
        for (int j = -1; j <= 2; ++j) {
            const int i = Fi + lane + j;             // 1-based time index
            const float dz = ((float)j - r) * inv_bw;
            const float w  = __expf(-0.5f * dz * dz);
            if (i >= 1 && i <= T_LEN) {
                const float2 p = lds[g][i - 1];
                wsum += w;
                accd = fmaf(w, p.x, accd);
                acco = fmaf(w, p.y, acco);
            }
        }
        out[row * K_LEN + lane] = ic41 - (accd + acco) / wsum;
    }
}

extern "C" void kernel_launch(void* const* d_in, const int* in_sizes, int n_in,
                              void* d_out, int out_size, void* d_ws, size_t ws_size,
                              hipStream_t stream) {
    const float* instock   = (const float*)d_in[0];
    const float* futured   = (const float*)d_in[1];
    const float* lead_pred = (const float*)d_in[2];
    float* out = (float*)d_out;
    (void)d_ws; (void)ws_size;

    const int B = in_sizes[0] / T_LEN;               // 65536
    const int grid = B / ROWS_PER_BLOCK;             // 8192

    pil_kernel<<<grid, BLOCK, 0, stream>>>(instock, futured, lead_pred, out, B);
}

// Round 4
// 75.522 us; speedup vs baseline: 1.3196x; 1.0944x over previous
//
#include <hip/hip_runtime.h>

#define T_LEN 41
#define K_LEN 28
#define ROWS_PER_BLOCK 8
#define BLOCK 256

// DPP-based inclusive scans (VALU, no LDS unit — replaces ds_bpermute shuffles).
// row_shr:d = 0x110|d ; row_bcast:15 = 0x142 (lane15 -> lanes16..31 within each
// 32-half, row_mask 0xA gates writes to odd 16-rows only). bound_ctrl=false,
// old = identity (0 for add, -inf for max) so invalid source lanes are no-ops.
#define DPP_ADD(x, ctrl, rmask)                                                  \
    x += __int_as_float(__builtin_amdgcn_update_dpp(                             \
        0, __float_as_int(x), ctrl, rmask, 0xF, false))
#define DPP_MAX(x, ctrl, rmask)                                                  \
    x = fmaxf(x, __int_as_float(__builtin_amdgcn_update_dpp(                     \
        (int)0xFF800000, __float_as_int(x), ctrl, rmask, 0xF, false)))

// inclusive add-scan across a 32-lane group
#define SCAN32_ADD(x)  do { DPP_ADD(x,0x111,0xF); DPP_ADD(x,0x112,0xF);          \
                            DPP_ADD(x,0x114,0xF); DPP_ADD(x,0x118,0xF);          \
                            DPP_ADD(x,0x142,0xA); } while (0)
#define SCAN32_MAX(x)  do { DPP_MAX(x,0x111,0xF); DPP_MAX(x,0x112,0xF);          \
                            DPP_MAX(x,0x114,0xF); DPP_MAX(x,0x118,0xF);          \
                            DPP_MAX(x,0x142,0xA); } while (0)
// scan confined to lanes 0..15 (tail holds 9 valid elements in lanes 0..8)
#define SCAN16_ADD(x)  do { DPP_ADD(x,0x111,0xF); DPP_ADD(x,0x112,0xF);          \
                            DPP_ADD(x,0x114,0xF); DPP_ADD(x,0x118,0xF); } while (0)
#define SCAN16_MAX(x)  do { DPP_MAX(x,0x111,0xF); DPP_MAX(x,0x112,0xF);          \
                            DPP_MAX(x,0x114,0xF); DPP_MAX(x,0x118,0xF); } while (0)

// broadcast lane `sel` of each 32-lane group to all 32 lanes (ds_swizzle BitMode:
// read lane (l&0)|sel — stays within the 32-group, unlike DPP row_bcast:31)
#define BCAST32(x, sel) __int_as_float(                                          \
    __builtin_amdgcn_ds_swizzle(__float_as_int(x), ((sel) << 5)))

__global__ __launch_bounds__(BLOCK) void pil_kernel(
    const float* __restrict__ instock,
    const float* __restrict__ futured,
    const float* __restrict__ lead_pred,
    float* __restrict__ out, int B)
{
    __shared__ float2 lds[ROWS_PER_BLOCK][T_LEN];   // {FC[i], OC[i]} at [i-1]

    const int g    = threadIdx.x >> 5;
    const int lane = threadIdx.x & 31;
    const int row  = blockIdx.x * ROWS_PER_BLOCK + g;

    const float lead = lead_pred[row];

    const float* __restrict__ f = futured + row * T_LEN;
    const float* __restrict__ s = instock + row * T_LEN;

    // loads: t = lane (0..31) and tail t = 32+lane (lane < 9)
    float fa = f[lane];
    float sa = s[lane];
    float fb = 0.f, sb = 0.f;
    if (lane < T_LEN - 32) { fb = f[32 + lane]; sb = s[32 + lane]; }

    // cumsums via DPP scans
    SCAN32_ADD(fa);
    SCAN32_ADD(sa);
    const float fc31 = BCAST32(fa, 31);
    const float ic31 = BCAST32(sa, 31);
    SCAN16_ADD(fb);
    SCAN16_ADD(sb);
    fb += fc31;
    sb += ic31;
    const float ic41 = BCAST32(sb, 8);              // instock_cumsum[:, -1]

    // cummax of diff (head relu at t=0)
    float da = sa - fa;
    if (lane == 0) da = fmaxf(da, 0.f);
    SCAN32_MAX(da);
    const float m31 = BCAST32(da, 31);
    float db = sb - fb;
    SCAN16_MAX(db);
    db = fmaxf(db, m31);

    // stash {FC, OC}
    lds[g][lane] = make_float2(fa, da);
    if (lane < T_LEN - 32) lds[g][32 + lane] = make_float2(fb, db);

    __syncthreads();

    // phase B: sigma=0.3 Gaussian -> only taps i = floor(ls)+k+j, j in {-1..2}
    // survive (dropped terms < e^-22); truncation to i in [1,41] matches the
    // reference's own normalization range exactly.
    if (lane < K_LEN) {
        const float ls = fminf(fmaxf(lead * 13.0f + 1.0f, 1.0f), 14.0f);
        const float Ff = floorf(ls);
        const float r  = ls - Ff;
        const int   Fi = (int)Ff;
        const float inv_bw = 1.0f / 0.3f;

        float wsum = 0.f, accd = 0.f, acco = 0.f;
        #pragma unroll
        for (int j = -1; j <= 2; ++j) {
            const int i = Fi + lane + j;             // 1-based time index
            const float dz = ((float)j - r) * inv_bw;
            const float w  = __expf(-0.5f * dz * dz);
            if (i >= 1 && i <= T_LEN) {
                const float2 p = lds[g][i - 1];
                wsum += w;
                accd = fmaf(w, p.x, accd);
                acco = fmaf(w, p.y, acco);
            }
        }
        out[row * K_LEN + lane] = ic41 - (accd + acco) / wsum;
    }
}

extern "C" void kernel_launch(void* const* d_in, const int* in_sizes, int n_in,
                              void* d_out, int out_size, void* d_ws, size_t ws_size,
                              hipStream_t stream) {
    const float* instock   = (const float*)d_in[0];
    const float* futured   = (const float*)d_in[1];
    const float* lead_pred = (const float*)d_in[2];
    float* out = (float*)d_out;
    (void)d_ws; (void)ws_size;

    const int B = in_sizes[0] / T_LEN;               // 65536
    const int grid = B / ROWS_PER_BLOCK;             // 8192

    pil_kernel<<<grid, BLOCK, 0, stream>>>(instock, futured, lead_pred, out, B);
}